// Round 1
// baseline (307.427 us; speedup 1.0000x reference)
//
#include <hip/hip_runtime.h>

#define GLOBAL_AS __attribute__((address_space(1)))
#define LDS_AS    __attribute__((address_space(3)))

typedef __bf16 bf16x8 __attribute__((ext_vector_type(8)));
typedef float  f32x4  __attribute__((ext_vector_type(4)));

// ---------- helpers ----------
__device__ inline unsigned short f2bf(float f) {
    unsigned int u = __float_as_uint(f);
    unsigned int r = (u + 0x7fffu + ((u >> 16) & 1u)) >> 16;  // RNE
    return (unsigned short)r;
}

// ---------- kernel 1: L2 normalize rows of 768 fp32 -> bf16 (as ushort) ----------
__global__ __launch_bounds__(256) void l2norm_kernel(const float* __restrict__ in,
                                                     unsigned short* __restrict__ out) {
    const int row = blockIdx.x;
    const int t = threadIdx.x;
    const float* p = in + (size_t)row * 768;
    float v0 = p[t], v1 = p[t + 256], v2 = p[t + 512];
    float ss = v0 * v0 + v1 * v1 + v2 * v2;
#pragma unroll
    for (int m = 1; m < 64; m <<= 1) ss += __shfl_xor(ss, m, 64);
    __shared__ float wsum[4];
    if ((t & 63) == 0) wsum[t >> 6] = ss;
    __syncthreads();
    float tot = wsum[0] + wsum[1] + wsum[2] + wsum[3];
    float scale = 1.0f / fmaxf(sqrtf(tot), 1e-12f);
    unsigned short* o = out + (size_t)row * 768;
    o[t]       = f2bf(v0 * scale);
    o[t + 256] = f2bf(v1 * scale);
    o[t + 512] = f2bf(v2 * scale);
}

// ---------- kernel 2: GEMM (A 16384x768 bf16) x (V 8192x768 bf16)^T with fused
// per-row max over each 128-col half-clip. Output rowhalf[(c*2+half)*16384 + row].
__global__ __launch_bounds__(256) void gemm_max_kernel(const unsigned short* __restrict__ A,
                                                       const unsigned short* __restrict__ V,
                                                       float* __restrict__ rowhalf) {
    __shared__ unsigned short AsU[128 * 64];
    __shared__ unsigned short BsU[128 * 64];
    __shared__ float pmax[2][128];

    const int t  = threadIdx.x;
    const int l  = t & 63;
    const int wv = t >> 6;      // wave 0..3
    const int wr = wv >> 1;     // wave row 0..1
    const int wc = wv & 1;      // wave col 0..1
    const int lr = l & 15;      // fragment row/col within 16
    const int kg = (l >> 4) * 8; // k-offset within 32-slice

    const int bx     = blockIdx.x;
    const int half   = bx & 1;
    const int c      = (bx >> 1) & 31;
    const int rowBlk = bx >> 6;

    const size_t aRow0 = (size_t)rowBlk * 128;
    const size_t vRow0 = (size_t)c * 256 + (size_t)half * 128;

    // staging: per issue q (0..3): LDS bytes [q*4096 + t*16, +16); row = q*32 + (t>>3)
    const int srow  = t >> 3;
    const int scolb = (t & 7) * 16;
    char* aSrc = (char*)A + (aRow0 + (size_t)srow) * 1536 + scolb;
    char* vSrc = (char*)V + (vRow0 + (size_t)srow) * 1536 + scolb;
    char* asBase = (char*)AsU;
    char* bsBase = (char*)BsU;

    f32x4 acc[4][4];
    const f32x4 zero = {0.0f, 0.0f, 0.0f, 0.0f};
#pragma unroll
    for (int i = 0; i < 4; i++)
#pragma unroll
        for (int j = 0; j < 4; j++) acc[i][j] = zero;

    for (int kt = 0; kt < 12; ++kt) {
        __syncthreads();  // previous tile's compute done before overwrite
        const int kb = kt * 128;  // byte offset along K
#pragma unroll
        for (int q = 0; q < 4; ++q) {
            __builtin_amdgcn_global_load_lds((GLOBAL_AS void*)(aSrc + kb + q * 32 * 1536),
                                             (LDS_AS void*)(asBase + q * 4096 + wv * 1024),
                                             16, 0, 0);
        }
#pragma unroll
        for (int q = 0; q < 4; ++q) {
            __builtin_amdgcn_global_load_lds((GLOBAL_AS void*)(vSrc + kb + q * 32 * 1536),
                                             (LDS_AS void*)(bsBase + q * 4096 + wv * 1024),
                                             16, 0, 0);
        }
        __syncthreads();  // compiler drains vmcnt(0) before barrier -> tile ready

#pragma unroll
        for (int ks = 0; ks < 2; ++ks) {
            bf16x8 af[4], bfr[4];
#pragma unroll
            for (int mi = 0; mi < 4; mi++)
                af[mi] = *(const bf16x8*)(AsU + (wr * 64 + mi * 16 + lr) * 64 + ks * 32 + kg);
#pragma unroll
            for (int ni = 0; ni < 4; ni++)
                bfr[ni] = *(const bf16x8*)(BsU + (wc * 64 + ni * 16 + lr) * 64 + ks * 32 + kg);
#pragma unroll
            for (int mi = 0; mi < 4; mi++)
#pragma unroll
                for (int ni = 0; ni < 4; ni++)
                    acc[mi][ni] = __builtin_amdgcn_mfma_f32_16x16x32_bf16(af[mi], bfr[ni],
                                                                          acc[mi][ni], 0, 0, 0);
        }
    }

    // epilogue: per output row, max over this wave's 64 columns
    // C/D layout: col = lane&15, row = (lane>>4)*4 + reg  (m89-verified)
#pragma unroll
    for (int mi = 0; mi < 4; mi++) {
#pragma unroll
        for (int j = 0; j < 4; j++) {
            float m = fmaxf(fmaxf(acc[mi][0][j], acc[mi][1][j]),
                            fmaxf(acc[mi][2][j], acc[mi][3][j]));
            m = fmaxf(m, __shfl_xor(m, 1, 64));
            m = fmaxf(m, __shfl_xor(m, 2, 64));
            m = fmaxf(m, __shfl_xor(m, 4, 64));
            m = fmaxf(m, __shfl_xor(m, 8, 64));
            if (lr == 0) pmax[wc][wr * 64 + mi * 16 + (l >> 4) * 4 + j] = m;
        }
    }
    __syncthreads();
    if (t < 128) {
        float m = fmaxf(pmax[0][t], pmax[1][t]);
        rowhalf[(size_t)(c * 2 + half) * 16384 + aRow0 + t] = m;
    }
}

// ---------- kernel 3: combine halves (max), mean over 512 rows -> clip_sims[32][32] ----------
__global__ __launch_bounds__(256) void reduce_rowmax_kernel(const float* __restrict__ rh,
                                                            float* __restrict__ clip) {
    const int b = blockIdx.x >> 5;
    const int c = blockIdx.x & 31;
    const int t = threadIdx.x;
    const float* p0 = rh + (size_t)(c * 2) * 16384 + (size_t)b * 512;
    const float* p1 = p0 + 16384;
    float s = 0.0f;
#pragma unroll
    for (int r = t; r < 512; r += 256) s += fmaxf(p0[r], p1[r]);
#pragma unroll
    for (int m = 1; m < 64; m <<= 1) s += __shfl_xor(s, m, 64);
    __shared__ float wsum[4];
    if ((t & 63) == 0) wsum[t >> 6] = s;
    __syncthreads();
    if (t == 0)
        clip[b * 32 + c] = (wsum[0] + wsum[1] + wsum[2] + wsum[3]) * (1.0f / 51.2f);
}

// ---------- kernel 4: log-softmax both ways on 32x32 + scalar loss ----------
__global__ __launch_bounds__(1024) void finalize_kernel(const float* __restrict__ clip,
                                                        float* __restrict__ out) {
    __shared__ float cs[32][33];
    __shared__ float rlse[32], clse[32];
    const int t = threadIdx.x;
    const int b = t >> 5, c = t & 31;
    cs[b][c] = clip[b * 32 + c];
    __syncthreads();
    if (t < 32) {
        float mx = -1e30f;
        for (int j = 0; j < 32; ++j) mx = fmaxf(mx, cs[t][j]);
        float s = 0.0f;
        for (int j = 0; j < 32; ++j) s += expf(cs[t][j] - mx);
        rlse[t] = mx + logf(s);
    } else if (t < 64) {
        const int cc = t - 32;
        float mx = -1e30f;
        for (int j = 0; j < 32; ++j) mx = fmaxf(mx, cs[j][cc]);
        float s = 0.0f;
        for (int j = 0; j < 32; ++j) s += expf(cs[j][cc] - mx);
        clse[cc] = mx + logf(s);
    }
    __syncthreads();
    if (t == 0) {
        float L = 0.0f;
        for (int i = 0; i < 32; ++i)
            L += -0.5f * (2.0f * cs[i][i] - rlse[i] - clse[i]);
        out[0] = L * (1.0f / 32.0f);
    }
}

extern "C" void kernel_launch(void* const* d_in, const int* in_sizes, int n_in,
                              void* d_out, int out_size, void* d_ws, size_t ws_size,
                              hipStream_t stream) {
    const float* audio  = (const float*)d_in[0];   // (32, 512, 768) f32
    const float* visual = (const float*)d_in[1];   // (32, 256, 768) f32

    unsigned short* aN = (unsigned short*)d_ws;                 // 16384*768 bf16
    unsigned short* vN = aN + (size_t)16384 * 768;              // 8192*768 bf16
    float* rowhalf = (float*)(vN + (size_t)8192 * 768);         // 64*16384 f32
    float* clip    = rowhalf + (size_t)64 * 16384;              // 1024 f32
    float* out     = (float*)d_out;

    l2norm_kernel<<<16384, 256, 0, stream>>>(audio, aN);
    l2norm_kernel<<<8192, 256, 0, stream>>>(visual, vN);
    gemm_max_kernel<<<8192, 256, 0, stream>>>(aN, vN, rowhalf);
    reduce_rowmax_kernel<<<1024, 256, 0, stream>>>(rowhalf, clip);
    finalize_kernel<<<1, 1024, 0, stream>>>(clip, out);
}

// Round 2
// 255.465 us; speedup vs baseline: 1.2034x; 1.2034x over previous
//
#include <hip/hip_runtime.h>

#define GLOBAL_AS __attribute__((address_space(1)))
#define LDS_AS    __attribute__((address_space(3)))

typedef __bf16 bf16x8 __attribute__((ext_vector_type(8)));
typedef float  f32x4  __attribute__((ext_vector_type(4)));

// ---------- helpers ----------
__device__ inline unsigned short f2bf(float f) {
    unsigned int u = __float_as_uint(f);
    return (unsigned short)((u + 0x7fffu + ((u >> 16) & 1u)) >> 16);  // RNE
}

// ---------- kernel 1: L2 normalize rows of 768 fp32 -> bf16 (as ushort) ----------
__global__ __launch_bounds__(256) void l2norm_kernel(const float* __restrict__ in,
                                                     unsigned short* __restrict__ out) {
    const int row = blockIdx.x;
    const int t = threadIdx.x;
    const float* p = in + (size_t)row * 768;
    float v0 = p[t], v1 = p[t + 256], v2 = p[t + 512];
    float ss = v0 * v0 + v1 * v1 + v2 * v2;
#pragma unroll
    for (int m = 1; m < 64; m <<= 1) ss += __shfl_xor(ss, m, 64);
    __shared__ float wsum[4];
    if ((t & 63) == 0) wsum[t >> 6] = ss;
    __syncthreads();
    float tot = wsum[0] + wsum[1] + wsum[2] + wsum[3];
    float scale = 1.0f / fmaxf(sqrtf(tot), 1e-12f);
    unsigned short* o = out + (size_t)row * 768;
    o[t]       = f2bf(v0 * scale);
    o[t + 256] = f2bf(v1 * scale);
    o[t + 512] = f2bf(v2 * scale);
}

// ---------- kernel 2: 256x256-tile 8-phase GEMM with fused per-clip row-max ----------
// A: 16384x768 bf16, V: 8192x768 bf16 (row-major, K contiguous). Each block:
// 256 audio rows x one clip (256 visual rows). Output rowmax[clip][16384].
//
// LDS (128 KiB): A dbuf{0,1} x half{0,1} @ (buf*2+h)*16384 ; B same @ +65536.
// Half-tile = 128 rows x 64 bf16 (128 B/row), st_16x32 swizzle: off ^= ((off>>9)&1)<<5.
// Stage: linear LDS dest (wave base + lane*16), inverse-swizzled global source.
// Stage seq per K-tile: {A0,B0,B1,A1}; in main loop phase p of kt stages:
//   P0: A1(kt+1) [other buf]  P1: A0(kt+2)  P2: B0(kt+2)  P3: B1(kt+2)
// (each lands >=1 barrier after the last ds_read of the half-tile it overwrites).
// One vmcnt(6) (3 half-tiles in flight) + s_barrier per K-tile boundary.

#define STAGE_A(KTJ, H) do {                                                          \
    const int _b = (KTJ) & 1;                                                         \
    char* _ld = smem + ((((_b) << 1) + (H)) << 14) + stageOff;                        \
    const size_t _go = (size_t)((H) * 196608) + (size_t)((KTJ) * 128);                \
    __builtin_amdgcn_global_load_lds((GLOBAL_AS void*)(aSrc0 + _go),                  \
                                     (LDS_AS void*)(_ld), 16, 0, 0);                  \
    __builtin_amdgcn_global_load_lds((GLOBAL_AS void*)(aSrc1 + _go),                  \
                                     (LDS_AS void*)(_ld + 8192), 16, 0, 0);           \
  } while (0)

#define STAGE_B(KTJ, H) do {                                                          \
    const int _b = (KTJ) & 1;                                                         \
    char* _ld = smem + 65536 + ((((_b) << 1) + (H)) << 14) + stageOff;                \
    const size_t _go = (size_t)((H) * 196608) + (size_t)((KTJ) * 128);                \
    __builtin_amdgcn_global_load_lds((GLOBAL_AS void*)(vSrc0 + _go),                  \
                                     (LDS_AS void*)(_ld), 16, 0, 0);                  \
    __builtin_amdgcn_global_load_lds((GLOBAL_AS void*)(vSrc1 + _go),                  \
                                     (LDS_AS void*)(_ld + 8192), 16, 0, 0);           \
  } while (0)

#define PHASE_BAR()  do {                                                             \
    __builtin_amdgcn_sched_barrier(0);                                                \
    __builtin_amdgcn_s_barrier();                                                     \
  } while (0)

#define MFMA16(ACCROW, BF) do {                                                       \
    asm volatile("s_waitcnt lgkmcnt(0)" ::: "memory");                                \
    __builtin_amdgcn_sched_barrier(0);                                                \
    __builtin_amdgcn_s_setprio(1);                                                    \
    _Pragma("unroll") for (int _mi = 0; _mi < 4; ++_mi)                               \
      _Pragma("unroll") for (int _ni = 0; _ni < 2; ++_ni) {                           \
        acc[ACCROW + _mi][(&BF[0][0] == &b1f[0][0]) ? _ni + 2 : _ni] =                \
            __builtin_amdgcn_mfma_f32_16x16x32_bf16(af[_mi][0], BF[_ni][0],           \
                acc[ACCROW + _mi][(&BF[0][0] == &b1f[0][0]) ? _ni + 2 : _ni], 0,0,0); \
        acc[ACCROW + _mi][(&BF[0][0] == &b1f[0][0]) ? _ni + 2 : _ni] =                \
            __builtin_amdgcn_mfma_f32_16x16x32_bf16(af[_mi][1], BF[_ni][1],           \
                acc[ACCROW + _mi][(&BF[0][0] == &b1f[0][0]) ? _ni + 2 : _ni], 0,0,0); \
      }                                                                               \
    __builtin_amdgcn_s_setprio(0);                                                    \
  } while (0)

#define KTILE(KT, S0, S123, VM) do {                                                  \
    const int _buf = (KT) & 1;                                                        \
    const char* _aB = smem + (((_buf << 1) + wm) << 14) + aOffBase;                   \
    const char* _bB = smem + 65536 + (((_buf << 1) + (wn >> 1)) << 14) + bOffBase;    \
    /* P0: read A-half(wm) mi0-3 + B ni0-1; stage A1(kt+1); compute q(0-3,0-1) */     \
    _Pragma("unroll") for (int mi = 0; mi < 4; ++mi) {                                \
      af[mi][0] = *(const bf16x8*)(_aB + mi * 2048);                                  \
      af[mi][1] = *(const bf16x8*)(_aB + mi * 2048 + 64);                             \
    }                                                                                 \
    _Pragma("unroll") for (int ni = 0; ni < 2; ++ni) {                                \
      b0f[ni][0] = *(const bf16x8*)(_bB + ni * 2048);                                 \
      b0f[ni][1] = *(const bf16x8*)(_bB + ni * 2048 + 64);                            \
    }                                                                                 \
    if (S0) { STAGE_A((KT) + 1, 1); }                                                 \
    PHASE_BAR();                                                                      \
    MFMA16(0, b0f);                                                                   \
    PHASE_BAR();                                                                      \
    /* P1: read B ni2-3; stage A0(kt+2); compute q(0-3,2-3) */                        \
    _Pragma("unroll") for (int ni = 0; ni < 2; ++ni) {                                \
      b1f[ni][0] = *(const bf16x8*)(_bB + (ni + 2) * 2048);                           \
      b1f[ni][1] = *(const bf16x8*)(_bB + (ni + 2) * 2048 + 64);                      \
    }                                                                                 \
    if (S123) { STAGE_A((KT) + 2, 0); }                                               \
    PHASE_BAR();                                                                      \
    MFMA16(0, b1f);                                                                   \
    PHASE_BAR();                                                                      \
    /* P2: read A mi4-7; stage B0(kt+2); compute q(4-7,0-1) */                        \
    _Pragma("unroll") for (int mi = 0; mi < 4; ++mi) {                                \
      af[mi][0] = *(const bf16x8*)(_aB + (mi + 4) * 2048);                            \
      af[mi][1] = *(const bf16x8*)(_aB + (mi + 4) * 2048 + 64);                       \
    }                                                                                 \
    if (S123) { STAGE_B((KT) + 2, 0); }                                               \
    PHASE_BAR();                                                                      \
    MFMA16(4, b0f);                                                                   \
    PHASE_BAR();                                                                      \
    /* P3: no reads; stage B1(kt+2); compute q(4-7,2-3); K-tile vmcnt checkpoint */   \
    if (S123) { STAGE_B((KT) + 2, 1); }                                               \
    PHASE_BAR();                                                                      \
    MFMA16(4, b1f);                                                                   \
    if ((VM) == 6)      asm volatile("s_waitcnt vmcnt(6)" ::: "memory");              \
    else if ((VM) == 0) asm volatile("s_waitcnt vmcnt(0)" ::: "memory");              \
    PHASE_BAR();                                                                      \
  } while (0)

__global__ __launch_bounds__(512, 2) void gemm_max_kernel(
    const unsigned short* __restrict__ A, const unsigned short* __restrict__ V,
    float* __restrict__ rowmax) {
    __shared__ __align__(1024) char smem[131072];

    const int tid = threadIdx.x;
    const int l   = tid & 63;
    const int wid = tid >> 6;
    const int wm  = wid >> 2;      // 0..1 : 128-row half of A tile
    const int wn  = wid & 3;       // 0..3 : 64-col slice of B tile
    const int lr  = l & 15;
    const int lg  = l >> 4;        // 0..3
    // swizzled read column-byte: cb = ks*64 + lg*16, XOR bit5 with row-bit2 (= lr>>2 bit0)
    const int cbe0     = (lg * 16) ^ (((lr >> 2) & 1) << 5);
    const int aOffBase = lr * 128 + cbe0;
    const int bOffBase = (wn & 1) * 8192 + lr * 128 + cbe0;
    const int stageOff = wid * 1024;

    const int bx  = blockIdx.x;                  // 2048 blocks, %8==0 -> bijective
    const int swz = (bx & 7) * 256 + (bx >> 3);  // XCD-aware swizzle
    const int rowBlk = swz >> 5;                 // 0..63
    const int clip   = swz & 31;                 // 0..31
    const size_t aRow0 = (size_t)rowBlk * 256;
    const size_t vRow0 = (size_t)clip * 256;

    // staging sources: linear LDS dest o -> global element at swz(o)
    const char *aSrc0, *aSrc1, *vSrc0, *vSrc1;
    {
        int o0 = tid * 16;
        int s0 = o0 ^ (((o0 >> 9) & 1) << 5);
        int o1 = 8192 + tid * 16;
        int s1 = o1 ^ (((o1 >> 9) & 1) << 5);
        aSrc0 = (const char*)A + (aRow0 + (s0 >> 7)) * 1536 + (s0 & 127);
        aSrc1 = (const char*)A + (aRow0 + (s1 >> 7)) * 1536 + (s1 & 127);
        vSrc0 = (const char*)V + (vRow0 + (s0 >> 7)) * 1536 + (s0 & 127);
        vSrc1 = (const char*)V + (vRow0 + (s1 >> 7)) * 1536 + (s1 & 127);
    }

    f32x4 acc[8][4];
    const f32x4 zero = {0.0f, 0.0f, 0.0f, 0.0f};
#pragma unroll
    for (int i = 0; i < 8; ++i)
#pragma unroll
        for (int j = 0; j < 4; ++j) acc[i][j] = zero;

    bf16x8 af[4][2], b0f[2][2], b1f[2][2];

    // prologue: stage kt0 {A0,B0,B1,A1} + kt1 {A0,B0,B1}; 3 half-tiles stay in flight
    STAGE_A(0, 0); STAGE_B(0, 0); STAGE_B(0, 1); STAGE_A(0, 1);
    asm volatile("s_waitcnt vmcnt(4)" ::: "memory");
    STAGE_A(1, 0); STAGE_B(1, 0); STAGE_B(1, 1);
    asm volatile("s_waitcnt vmcnt(6)" ::: "memory");
    PHASE_BAR();

#pragma unroll 1
    for (int kt = 0; kt < 10; ++kt) { KTILE(kt, 1, 1, 6); }
    KTILE(10, 1, 0, 0);
    KTILE(11, 0, 0, -1);

    // epilogue: fused row-max over the clip's 256 visual cols
    __syncthreads();
    float* pm = (float*)smem;  // [256 rows][4 wn] partial maxes
#pragma unroll
    for (int mi = 0; mi < 8; ++mi) {
#pragma unroll
        for (int j = 0; j < 4; ++j) {
            float m = fmaxf(fmaxf(acc[mi][0][j], acc[mi][1][j]),
                            fmaxf(acc[mi][2][j], acc[mi][3][j]));
            m = fmaxf(m, __shfl_xor(m, 1, 64));
            m = fmaxf(m, __shfl_xor(m, 2, 64));
            m = fmaxf(m, __shfl_xor(m, 4, 64));
            m = fmaxf(m, __shfl_xor(m, 8, 64));
            if (lr == 0) pm[(wm * 128 + mi * 16 + lg * 4 + j) * 4 + wn] = m;
        }
    }
    __syncthreads();
    if (tid < 256) {
        float m = fmaxf(fmaxf(pm[tid * 4], pm[tid * 4 + 1]),
                        fmaxf(pm[tid * 4 + 2], pm[tid * 4 + 3]));
        rowmax[(size_t)clip * 16384 + aRow0 + tid] = m;
    }
}

// ---------- kernel 3: mean over 512 audio rows -> clip_sims[32][32] (incl. 1/temp) ----------
__global__ __launch_bounds__(256) void reduce_mean_kernel(const float* __restrict__ rm,
                                                          float* __restrict__ clip) {
    const int b = blockIdx.x >> 5;
    const int c = blockIdx.x & 31;
    const int t = threadIdx.x;
    const float* p = rm + (size_t)c * 16384 + (size_t)b * 512;
    float s = p[t] + p[t + 256];
#pragma unroll
    for (int m = 1; m < 64; m <<= 1) s += __shfl_xor(s, m, 64);
    __shared__ float wsum[4];
    if ((t & 63) == 0) wsum[t >> 6] = s;
    __syncthreads();
    if (t == 0)
        clip[b * 32 + c] = (wsum[0] + wsum[1] + wsum[2] + wsum[3]) * (1.0f / 51.2f);
}

// ---------- kernel 4: log-softmax both ways on 32x32 + scalar loss ----------
__global__ __launch_bounds__(1024) void finalize_kernel(const float* __restrict__ clip,
                                                        float* __restrict__ out) {
    __shared__ float cs[32][33];
    __shared__ float rlse[32], clse[32];
    const int t = threadIdx.x;
    const int b = t >> 5, c = t & 31;
    cs[b][c] = clip[b * 32 + c];
    __syncthreads();
    if (t < 32) {
        float mx = -1e30f;
        for (int j = 0; j < 32; ++j) mx = fmaxf(mx, cs[t][j]);
        float s = 0.0f;
        for (int j = 0; j < 32; ++j) s += expf(cs[t][j] - mx);
        rlse[t] = mx + logf(s);
    } else if (t < 64) {
        const int cc = t - 32;
        float mx = -1e30f;
        for (int j = 0; j < 32; ++j) mx = fmaxf(mx, cs[j][cc]);
        float s = 0.0f;
        for (int j = 0; j < 32; ++j) s += expf(cs[j][cc] - mx);
        clse[cc] = mx + logf(s);
    }
    __syncthreads();
    if (t == 0) {
        float L = 0.0f;
        for (int i = 0; i < 32; ++i)
            L += -0.5f * (2.0f * cs[i][i] - rlse[i] - clse[i]);
        out[0] = L * (1.0f / 32.0f);
    }
}

extern "C" void kernel_launch(void* const* d_in, const int* in_sizes, int n_in,
                              void* d_out, int out_size, void* d_ws, size_t ws_size,
                              hipStream_t stream) {
    const float* audio  = (const float*)d_in[0];   // (32, 512, 768) f32
    const float* visual = (const float*)d_in[1];   // (32, 256, 768) f32

    unsigned short* aN = (unsigned short*)d_ws;                 // 16384*768 bf16
    unsigned short* vN = aN + (size_t)16384 * 768;              // 8192*768 bf16
    float* rowmax = (float*)(vN + (size_t)8192 * 768);          // 32*16384 f32
    float* clip   = rowmax + (size_t)32 * 16384;                // 1024 f32
    float* out    = (float*)d_out;

    l2norm_kernel<<<16384, 256, 0, stream>>>(audio, aN);
    l2norm_kernel<<<8192, 256, 0, stream>>>(visual, vN);
    gemm_max_kernel<<<2048, 512, 0, stream>>>(aN, vN, rowmax);
    reduce_mean_kernel<<<1024, 256, 0, stream>>>(rowmax, clip);
    finalize_kernel<<<1, 1024, 0, stream>>>(clip, out);
}

// Round 3
// 237.947 us; speedup vs baseline: 1.2920x; 1.0736x over previous
//
#include <hip/hip_runtime.h>

#define GLOBAL_AS __attribute__((address_space(1)))
#define LDS_AS    __attribute__((address_space(3)))

typedef __bf16 bf16x8 __attribute__((ext_vector_type(8)));
typedef float  f32x4  __attribute__((ext_vector_type(4)));
typedef unsigned short u16x4 __attribute__((ext_vector_type(4)));

// ---------- helpers ----------
__device__ inline unsigned short f2bf(float f) {
    unsigned int u = __float_as_uint(f);
    return (unsigned short)((u + 0x7fffu + ((u >> 16) & 1u)) >> 16);  // RNE
}

// ---------- kernel 1: fused L2 normalize (audio then visual), 1 wave/row ----------
// in: rows of 768 f32; out: bf16 rows, aN (16384 rows) then vN (8192 rows) contiguous.
__global__ __launch_bounds__(256) void l2norm_kernel(const float* __restrict__ audio,
                                                     const float* __restrict__ visual,
                                                     unsigned short* __restrict__ out) {
    const int gw = blockIdx.x * 4 + (threadIdx.x >> 6);  // global row 0..24575
    const int l  = threadIdx.x & 63;
    const float* src = (gw < 16384) ? (audio + (size_t)gw * 768)
                                    : (visual + ((size_t)gw - 16384) * 768);
    const float4* p = (const float4*)src;
    float4 a = p[l], b = p[l + 64], c = p[l + 128];
    float ss = a.x * a.x + a.y * a.y + a.z * a.z + a.w * a.w
             + b.x * b.x + b.y * b.y + b.z * b.z + b.w * b.w
             + c.x * c.x + c.y * c.y + c.z * c.z + c.w * c.w;
#pragma unroll
    for (int m = 1; m < 64; m <<= 1) ss += __shfl_xor(ss, m, 64);
    const float s = 1.0f / fmaxf(sqrtf(ss), 1e-12f);
    u16x4* o = (u16x4*)(out + (size_t)gw * 768);
    u16x4 u0 = {f2bf(a.x * s), f2bf(a.y * s), f2bf(a.z * s), f2bf(a.w * s)};
    u16x4 u1 = {f2bf(b.x * s), f2bf(b.y * s), f2bf(b.z * s), f2bf(b.w * s)};
    u16x4 u2 = {f2bf(c.x * s), f2bf(c.y * s), f2bf(c.z * s), f2bf(c.w * s)};
    o[l] = u0; o[l + 64] = u1; o[l + 128] = u2;
}

// ---------- kernel 2: 256x256-tile 8-phase GEMM with fused per-clip row-max ----------
// A: 16384x768 bf16, V: 8192x768 bf16 (row-major, K contiguous). Each block:
// 256 audio rows x one clip (256 visual rows). Output rowmax[clip][16384].
//
// LDS (128 KiB): A dbuf{0,1} x half{0,1} @ (buf*2+h)*16384 ; B same @ +65536.
// Half-tile = 128 rows x 64 bf16 (128 B/row). Flat-layout bank swizzle:
//   phys_cb = logical_cb ^ ((row & 7) << 4)   (involution, bijective per row)
// Stage: linear LDS dest (wave base + lane*16), inverse-swizzled global source
// (rule #21: both-sides-or-neither). Reads spread each ds_read_b128's 64 lanes
// across all 8 granules / 32 banks = conflict floor.
// Stage seq per K-tile: {A0,B0,B1,A1}; one vmcnt(6) + barrier per K-tile.

#define STAGE_A(KTJ, H) do {                                                          \
    const int _b = (KTJ) & 1;                                                         \
    char* _ld = smem + ((((_b) << 1) + (H)) << 14) + stageOff;                        \
    const size_t _go = (size_t)((H) * 196608) + (size_t)((KTJ) * 128);                \
    __builtin_amdgcn_global_load_lds((GLOBAL_AS void*)(aSrc0 + _go),                  \
                                     (LDS_AS void*)(_ld), 16, 0, 0);                  \
    __builtin_amdgcn_global_load_lds((GLOBAL_AS void*)(aSrc1 + _go),                  \
                                     (LDS_AS void*)(_ld + 8192), 16, 0, 0);           \
  } while (0)

#define STAGE_B(KTJ, H) do {                                                          \
    const int _b = (KTJ) & 1;                                                         \
    char* _ld = smem + 65536 + ((((_b) << 1) + (H)) << 14) + stageOff;                \
    const size_t _go = (size_t)((H) * 196608) + (size_t)((KTJ) * 128);                \
    __builtin_amdgcn_global_load_lds((GLOBAL_AS void*)(vSrc0 + _go),                  \
                                     (LDS_AS void*)(_ld), 16, 0, 0);                  \
    __builtin_amdgcn_global_load_lds((GLOBAL_AS void*)(vSrc1 + _go),                  \
                                     (LDS_AS void*)(_ld + 8192), 16, 0, 0);           \
  } while (0)

#define PHASE_BAR()  do {                                                             \
    __builtin_amdgcn_sched_barrier(0);                                                \
    __builtin_amdgcn_s_barrier();                                                     \
  } while (0)

#define MFMA16(ACCROW, BF) do {                                                       \
    asm volatile("s_waitcnt lgkmcnt(0)" ::: "memory");                                \
    __builtin_amdgcn_sched_barrier(0);                                                \
    __builtin_amdgcn_s_setprio(1);                                                    \
    _Pragma("unroll") for (int _mi = 0; _mi < 4; ++_mi)                               \
      _Pragma("unroll") for (int _ni = 0; _ni < 2; ++_ni) {                           \
        acc[ACCROW + _mi][(&BF[0][0] == &b1f[0][0]) ? _ni + 2 : _ni] =                \
            __builtin_amdgcn_mfma_f32_16x16x32_bf16(af[_mi][0], BF[_ni][0],           \
                acc[ACCROW + _mi][(&BF[0][0] == &b1f[0][0]) ? _ni + 2 : _ni], 0,0,0); \
        acc[ACCROW + _mi][(&BF[0][0] == &b1f[0][0]) ? _ni + 2 : _ni] =                \
            __builtin_amdgcn_mfma_f32_16x16x32_bf16(af[_mi][1], BF[_ni][1],           \
                acc[ACCROW + _mi][(&BF[0][0] == &b1f[0][0]) ? _ni + 2 : _ni], 0,0,0); \
      }                                                                               \
    __builtin_amdgcn_s_setprio(0);                                                    \
  } while (0)

#define KTILE(KT, S0, S123, VM) do {                                                  \
    const int _buf = (KT) & 1;                                                        \
    const char* _aT = smem + (((_buf << 1) + wm) << 14);                              \
    const char* _bT = smem + 65536 + (((_buf << 1) + (wn >> 1)) << 14);               \
    const char* _aB0 = _aT + aOff0;                                                   \
    const char* _aB1 = _aT + aOff1;                                                   \
    const char* _bB0 = _bT + bOff0;                                                   \
    const char* _bB1 = _bT + bOff1;                                                   \
    /* P0: read A-half(wm) mi0-3 + B ni0-1; stage A1(kt+1); compute q(0-3,0-1) */     \
    _Pragma("unroll") for (int mi = 0; mi < 4; ++mi) {                                \
      af[mi][0] = *(const bf16x8*)(_aB0 + mi * 2048);                                 \
      af[mi][1] = *(const bf16x8*)(_aB1 + mi * 2048);                                 \
    }                                                                                 \
    _Pragma("unroll") for (int ni = 0; ni < 2; ++ni) {                                \
      b0f[ni][0] = *(const bf16x8*)(_bB0 + ni * 2048);                                \
      b0f[ni][1] = *(const bf16x8*)(_bB1 + ni * 2048);                                \
    }                                                                                 \
    if (S0) { STAGE_A((KT) + 1, 1); }                                                 \
    PHASE_BAR();                                                                      \
    MFMA16(0, b0f);                                                                   \
    PHASE_BAR();                                                                      \
    /* P1: read B ni2-3; stage A0(kt+2); compute q(0-3,2-3) */                        \
    _Pragma("unroll") for (int ni = 0; ni < 2; ++ni) {                                \
      b1f[ni][0] = *(const bf16x8*)(_bB0 + (ni + 2) * 2048);                          \
      b1f[ni][1] = *(const bf16x8*)(_bB1 + (ni + 2) * 2048);                          \
    }                                                                                 \
    if (S123) { STAGE_A((KT) + 2, 0); }                                               \
    PHASE_BAR();                                                                      \
    MFMA16(0, b1f);                                                                   \
    PHASE_BAR();                                                                      \
    /* P2: read A mi4-7; stage B0(kt+2); compute q(4-7,0-1) */                        \
    _Pragma("unroll") for (int mi = 0; mi < 4; ++mi) {                                \
      af[mi][0] = *(const bf16x8*)(_aB0 + (mi + 4) * 2048);                           \
      af[mi][1] = *(const bf16x8*)(_aB1 + (mi + 4) * 2048);                           \
    }                                                                                 \
    if (S123) { STAGE_B((KT) + 2, 0); }                                               \
    PHASE_BAR();                                                                      \
    MFMA16(4, b0f);                                                                   \
    PHASE_BAR();                                                                      \
    /* P3: no reads; stage B1(kt+2); compute q(4-7,2-3); K-tile vmcnt checkpoint */   \
    if (S123) { STAGE_B((KT) + 2, 1); }                                               \
    PHASE_BAR();                                                                      \
    MFMA16(4, b1f);                                                                   \
    if ((VM) == 6)      asm volatile("s_waitcnt vmcnt(6)" ::: "memory");              \
    else if ((VM) == 0) asm volatile("s_waitcnt vmcnt(0)" ::: "memory");              \
    PHASE_BAR();                                                                      \
  } while (0)

__global__ __launch_bounds__(512, 2) void gemm_max_kernel(
    const unsigned short* __restrict__ A, const unsigned short* __restrict__ V,
    float* __restrict__ rowmax) {
    __shared__ __align__(1024) char smem[131072];

    const int tid = threadIdx.x;
    const int l   = tid & 63;
    const int wid = tid >> 6;
    const int wm  = wid >> 2;      // 0..1 : 128-row half of A tile
    const int wn  = wid & 3;       // 0..3 : 64-col slice of B tile
    const int lr  = l & 15;
    const int lg  = l >> 4;        // 0..3
    // flat-layout swizzle: phys_cb = logical_cb ^ ((row&7)<<4); row&7 == lr&7
    const int swzr = (lr & 7) << 4;
    const int cbLo = (lg * 16) ^ swzr;         // logical K bytes [0,64)
    const int cbHi = (64 + lg * 16) ^ swzr;    // logical K bytes [64,128)
    const int aOff0 = lr * 128 + cbLo;
    const int aOff1 = lr * 128 + cbHi;
    const int bOff0 = (wn & 1) * 8192 + lr * 128 + cbLo;
    const int bOff1 = (wn & 1) * 8192 + lr * 128 + cbHi;
    const int stageOff = wid * 1024;

    const int bx  = blockIdx.x;                  // 2048 blocks, %8==0 -> bijective
    const int swz = (bx & 7) * 256 + (bx >> 3);  // XCD-aware swizzle
    const int rowBlk = swz >> 5;                 // 0..63
    const int clip   = swz & 31;                 // 0..31
    const size_t aRow0 = (size_t)rowBlk * 256;
    const size_t vRow0 = (size_t)clip * 256;

    // staging sources: linear LDS offset o (row=o>>7, cb=o&127) <- global
    // element at (row, cb ^ ((row&7)<<4)). Chunk1 is +64 rows; 64%8==0 so
    // the swizzle term is identical -> constant pointer offset.
    const char *aSrc0, *aSrc1, *vSrc0, *vSrc1;
    {
        const int r0 = tid >> 3;                                     // 0..63
        const int cb = ((tid & 7) * 16) ^ ((r0 & 7) << 4);
        aSrc0 = (const char*)A + (aRow0 + r0) * 1536 + cb;
        aSrc1 = aSrc0 + 64 * 1536;
        vSrc0 = (const char*)V + (vRow0 + r0) * 1536 + cb;
        vSrc1 = vSrc0 + 64 * 1536;
    }

    f32x4 acc[8][4];
    const f32x4 zero = {0.0f, 0.0f, 0.0f, 0.0f};
#pragma unroll
    for (int i = 0; i < 8; ++i)
#pragma unroll
        for (int j = 0; j < 4; ++j) acc[i][j] = zero;

    bf16x8 af[4][2], b0f[2][2], b1f[2][2];

    // prologue: stage kt0 {A0,B0,B1,A1} + kt1 {A0,B0,B1}; 3 half-tiles in flight
    STAGE_A(0, 0); STAGE_B(0, 0); STAGE_B(0, 1); STAGE_A(0, 1);
    asm volatile("s_waitcnt vmcnt(4)" ::: "memory");
    STAGE_A(1, 0); STAGE_B(1, 0); STAGE_B(1, 1);
    asm volatile("s_waitcnt vmcnt(6)" ::: "memory");
    PHASE_BAR();

#pragma unroll 1
    for (int kt = 0; kt < 10; ++kt) { KTILE(kt, 1, 1, 6); }
    KTILE(10, 1, 0, 0);
    KTILE(11, 0, 0, -1);

    // epilogue: fused row-max over the clip's 256 visual cols
    __syncthreads();
    float* pm = (float*)smem;  // [256 rows][4 wn] partial maxes
#pragma unroll
    for (int mi = 0; mi < 8; ++mi) {
#pragma unroll
        for (int j = 0; j < 4; ++j) {
            float m = fmaxf(fmaxf(acc[mi][0][j], acc[mi][1][j]),
                            fmaxf(acc[mi][2][j], acc[mi][3][j]));
            m = fmaxf(m, __shfl_xor(m, 1, 64));
            m = fmaxf(m, __shfl_xor(m, 2, 64));
            m = fmaxf(m, __shfl_xor(m, 4, 64));
            m = fmaxf(m, __shfl_xor(m, 8, 64));
            if (lr == 0) pm[(wm * 128 + mi * 16 + lg * 4 + j) * 4 + wn] = m;
        }
    }
    __syncthreads();
    if (tid < 256) {
        float m = fmaxf(fmaxf(pm[tid * 4], pm[tid * 4 + 1]),
                        fmaxf(pm[tid * 4 + 2], pm[tid * 4 + 3]));
        rowmax[(size_t)clip * 16384 + aRow0 + tid] = m;
    }
}

// ---------- kernel 3: mean over 512 audio rows -> clip_sims[32][32] (incl. 1/temp) ----------
__global__ __launch_bounds__(256) void reduce_mean_kernel(const float* __restrict__ rm,
                                                          float* __restrict__ clip) {
    const int b = blockIdx.x >> 5;
    const int c = blockIdx.x & 31;
    const int t = threadIdx.x;
    const float* p = rm + (size_t)c * 16384 + (size_t)b * 512;
    float s = p[t] + p[t + 256];
#pragma unroll
    for (int m = 1; m < 64; m <<= 1) s += __shfl_xor(s, m, 64);
    __shared__ float wsum[4];
    if ((t & 63) == 0) wsum[t >> 6] = s;
    __syncthreads();
    if (t == 0)
        clip[b * 32 + c] = (wsum[0] + wsum[1] + wsum[2] + wsum[3]) * (1.0f / 51.2f);
}

// ---------- kernel 4: log-softmax both ways on 32x32 + scalar loss ----------
__global__ __launch_bounds__(1024) void finalize_kernel(const float* __restrict__ clip,
                                                        float* __restrict__ out) {
    __shared__ float cs[32][33];
    __shared__ float rlse[32], clse[32];
    const int t = threadIdx.x;
    const int b = t >> 5, c = t & 31;
    cs[b][c] = clip[b * 32 + c];
    __syncthreads();
    if (t < 32) {
        float mx = -1e30f;
        for (int j = 0; j < 32; ++j) mx = fmaxf(mx, cs[t][j]);
        float s = 0.0f;
        for (int j = 0; j < 32; ++j) s += expf(cs[t][j] - mx);
        rlse[t] = mx + logf(s);
    } else if (t < 64) {
        const int cc = t - 32;
        float mx = -1e30f;
        for (int j = 0; j < 32; ++j) mx = fmaxf(mx, cs[j][cc]);
        float s = 0.0f;
        for (int j = 0; j < 32; ++j) s += expf(cs[j][cc] - mx);
        clse[cc] = mx + logf(s);
    }
    __syncthreads();
    if (t == 0) {
        float L = 0.0f;
        for (int i = 0; i < 32; ++i)
            L += -0.5f * (2.0f * cs[i][i] - rlse[i] - clse[i]);
        out[0] = L * (1.0f / 32.0f);
    }
}

extern "C" void kernel_launch(void* const* d_in, const int* in_sizes, int n_in,
                              void* d_out, int out_size, void* d_ws, size_t ws_size,
                              hipStream_t stream) {
    const float* audio  = (const float*)d_in[0];   // (32, 512, 768) f32
    const float* visual = (const float*)d_in[1];   // (32, 256, 768) f32

    unsigned short* aN = (unsigned short*)d_ws;                 // 16384*768 bf16
    unsigned short* vN = aN + (size_t)16384 * 768;              // 8192*768 bf16
    float* rowmax = (float*)(vN + (size_t)8192 * 768);          // 32*16384 f32
    float* clip   = rowmax + (size_t)32 * 16384;                // 1024 f32
    float* out    = (float*)d_out;

    l2norm_kernel<<<6144, 256, 0, stream>>>(audio, visual, aN);
    gemm_max_kernel<<<2048, 512, 0, stream>>>(aN, vN, rowmax);
    reduce_mean_kernel<<<1024, 256, 0, stream>>>(rowmax, clip);
    finalize_kernel<<<1, 1024, 0, stream>>>(clip, out);
}